// Round 1
// 362.828 us; speedup vs baseline: 1.0975x; 1.0975x over previous
//
#include <hip/hip_runtime.h>
#include <hip/hip_fp16.h>

#define N_NODES 100000
#define KK 5
#define CC 16
#define EE 3200000
#define NXCC 8

#define NB 16                // row buckets
#define ROWS_PB 6250         // N_NODES / NB
#define WCAP 512             // entries per (block,bucket) window: mean 320, +11 sigma
#define BPB 96               // accum blocks per bucket (16*96 = 1536 blocks, 6/CU)
#define CHUNK 5120           // edges per scatter block
#define NCHUNK 3125          // 3125 * 5120 = 16,000,000
#define GROUPS 5             // CHUNK / (256*4)
#define BLK_PER_K 625        // EE / CHUNK

__device__ __forceinline__ int xcc_id() {
    int x;
    asm volatile("s_getreg_b32 %0, hwreg(HW_REG_XCC_ID)" : "=s"(x));
    return x & (NXCC - 1);
}

// Kernel 1: Zt[k*N + n] = sum_c X[n,c] * h[c,k]
__global__ void compute_z_kernel(const float* __restrict__ X,
                                 const float* __restrict__ h,
                                 float* __restrict__ Zt) {
    int n = blockIdx.x * blockDim.x + threadIdx.x;
    if (n >= N_NODES) return;
    const float4* Xr = (const float4*)(X + (size_t)n * CC);
    float4 x0 = Xr[0], x1 = Xr[1], x2 = Xr[2], x3 = Xr[3];
    float xv[CC] = {x0.x, x0.y, x0.z, x0.w, x1.x, x1.y, x1.z, x1.w,
                    x2.x, x2.y, x2.z, x2.w, x3.x, x3.y, x3.z, x3.w};
#pragma unroll
    for (int k = 0; k < KK; ++k) {
        float acc = 0.0f;
#pragma unroll
        for (int c = 0; c < CC; ++c) acc += xv[c] * h[c * KK + k];
        Zt[k * N_NODES + n] = acc;
    }
}

// Phase A, MLP-restructured (R5): old version ran at VGPR_Count=12, pure
// latency-bound (VALUBusy 4.5%, HBM 13%) -- each edge a serial
// load->gather->atomic->store chain. Now phase-structured per block chunk:
//   1) 15 coalesced input loads issued back-to-back (r/c/v for all 5 groups)
//   2) all 20 Zk gathers issued back-to-back (~20 outstanding misses/wave)
//   3) all 20 LDS position atomics (depend only on rows -> overlap gathers)
//   4) single wait -> pack fp16 + store
// binned layout now bucket-major [b][w][WCAP] so Phase B streams.
__global__ void scatter_kernel(const int* __restrict__ rows,
                               const int* __restrict__ cols,
                               const float* __restrict__ vals,
                               const float* __restrict__ Zt,
                               unsigned int* __restrict__ binned,
                               int* __restrict__ counts,
                               float* __restrict__ spill) {
    __shared__ int lcnt[NB];
    int tid = threadIdx.x;
    if (tid < NB) lcnt[tid] = 0;
    __syncthreads();

    int w = blockIdx.x;
    int cbase = w * CHUNK;
    const float* Zk = Zt + (size_t)(w / BLK_PER_K) * N_NODES;   // block shares one k

    // ---- phase 1: all inputs (60 VGPRs, 15 dwordx4 loads in flight) ----
    int4   r4[GROUPS], c4[GROUPS];
    float4 v4[GROUPS];
#pragma unroll
    for (int g = 0; g < GROUPS; ++g) {
        int e = cbase + (g * 256 + tid) * 4;
        r4[g] = *(const int4*)(rows + e);
        c4[g] = *(const int4*)(cols + e);
        v4[g] = *(const float4*)(vals + e);
    }

    // ---- phase 2: all 20 gathers issued before any consumer ----
    float z[GROUPS * 4];
#pragma unroll
    for (int g = 0; g < GROUPS; ++g) {
        z[4 * g + 0] = Zk[c4[g].x];
        z[4 * g + 1] = Zk[c4[g].y];
        z[4 * g + 2] = Zk[c4[g].z];
        z[4 * g + 3] = Zk[c4[g].w];
    }

    // ---- phase 3: LDS position allocation, overlaps in-flight gathers ----
    int pos[GROUPS * 4];
#pragma unroll
    for (int g = 0; g < GROUPS; ++g) {
        int rr[4] = {r4[g].x, r4[g].y, r4[g].z, r4[g].w};
#pragma unroll
        for (int i = 0; i < 4; ++i) {
            int b = rr[i] / ROWS_PB;                  // compiler magic-mul
            pos[4 * g + i] = atomicAdd(&lcnt[b], 1);
        }
    }

    // ---- phase 4: pack + store (waits gathers once) ----
    unsigned int* wbase = binned + (size_t)w * WCAP;  // + b * (NCHUNK*WCAP)
#pragma unroll
    for (int g = 0; g < GROUPS; ++g) {
        int   rr[4] = {r4[g].x, r4[g].y, r4[g].z, r4[g].w};
        float vv[4] = {v4[g].x, v4[g].y, v4[g].z, v4[g].w};
#pragma unroll
        for (int i = 0; i < 4; ++i) {
            int b = rr[i] / ROWS_PB;
            float cb = vv[i] * z[4 * g + i];
            int p = pos[4 * g + i];
            if (p < WCAP) {
                unsigned int packed =
                    ((unsigned)(rr[i] - b * ROWS_PB) << 16) |
                    (unsigned)__half_as_ushort(__float2half_rn(cb));
                wbase[(size_t)b * (NCHUNK * WCAP) + p] = packed;
            } else {
                unsafeAtomicAdd(&spill[rr[i]], cb);   // exact, ~never taken
            }
        }
    }
    __syncthreads();
    if (tid < NB) counts[w * NB + tid] = min(lcnt[tid], WCAP);
}

// Phase B, MLP-restructured: counts preloaded to LDS once; 4 windows x 2
// position-strips = 8 independent loads in flight per thread, then the
// ds_add burst. binned is bucket-major so the read stream is near-contiguous.
__global__ void accum_kernel(const unsigned int* __restrict__ binned,
                             const int* __restrict__ counts,
                             float* __restrict__ partials) {
    __shared__ float acc[ROWS_PB];                    // 25 KB
    __shared__ int cnts[40];                          // whi-wlo <= 33
    int b = blockIdx.x / BPB;
    int s = blockIdx.x % BPB;
    int tid = threadIdx.x;
    int wlo = (NCHUNK * s) / BPB;
    int whi = (NCHUNK * (s + 1)) / BPB;
    for (int i = tid; i < ROWS_PB; i += 256) acc[i] = 0.0f;
    if (tid < whi - wlo) cnts[tid] = counts[(wlo + tid) * NB + b];
    __syncthreads();

    const unsigned int* bbase = binned + (size_t)b * (NCHUNK * WCAP);
    for (int w0 = wlo; w0 < whi; w0 += 4) {
        unsigned int e[8];
        int ok[8];
#pragma unroll
        for (int j = 0; j < 4; ++j) {
            int w = w0 + j;
            int cnt = (w < whi) ? cnts[w - wlo] : 0;
            const unsigned int* src = bbase + (size_t)w * WCAP;
            ok[2 * j]     = tid < cnt;
            ok[2 * j + 1] = tid + 256 < cnt;
            e[2 * j]      = ok[2 * j]     ? src[tid]       : 0u;
            e[2 * j + 1]  = ok[2 * j + 1] ? src[tid + 256] : 0u;
        }
#pragma unroll
        for (int q = 0; q < 8; ++q)
            if (ok[q])
                atomicAdd(&acc[e[q] >> 16],
                          __half2float(__ushort_as_half((unsigned short)(e[q] & 0xFFFFu))));
    }
    __syncthreads();
    float* dst = partials + (size_t)blockIdx.x * ROWS_PB;
    for (int i = tid; i < ROWS_PB; i += 256) dst[i] = acc[i];
}

// y[n] = spill[n] + sum over BPB partial slices of n's bucket
__global__ void reduce_kernel(const float* __restrict__ partials,
                              const float* __restrict__ spill,
                              float* __restrict__ y) {
    int n = blockIdx.x * blockDim.x + threadIdx.x;
    if (n >= N_NODES) return;
    int b = n / ROWS_PB, loc = n - b * ROWS_PB;
    const float* p = partials + (size_t)(b * BPB) * ROWS_PB + loc;
    float acc = spill[n];
#pragma unroll 8
    for (int s = 0; s < BPB; ++s) acc += p[(size_t)s * ROWS_PB];
    y[n] = acc;
}

// ---------- fallback path (R3): far-atomic scatter, used if ws too small ----
__global__ void edge_kernel_atomic(const int* __restrict__ rows,
                                   const int* __restrict__ cols,
                                   const float* __restrict__ vals,
                                   const float* __restrict__ Zt,
                                   float* __restrict__ yrep) {
    int t = blockIdx.x * blockDim.x + threadIdx.x;
    int base = t * 4;
    if (base >= KK * EE) return;
    int k = base / EE;
    const float* Zk = Zt + (size_t)k * N_NODES;
    float* y = yrep + (size_t)xcc_id() * N_NODES;
    int4 r = *(const int4*)(rows + base);
    int4 c = *(const int4*)(cols + base);
    float4 v = *(const float4*)(vals + base);
    unsafeAtomicAdd(&y[r.x], v.x * Zk[c.x]);
    unsafeAtomicAdd(&y[r.y], v.y * Zk[c.y]);
    unsafeAtomicAdd(&y[r.z], v.z * Zk[c.z]);
    unsafeAtomicAdd(&y[r.w], v.w * Zk[c.w]);
}

__global__ void reduce8_kernel(const float* __restrict__ yrep, float* __restrict__ y) {
    int n = blockIdx.x * blockDim.x + threadIdx.x;
    if (n >= N_NODES) return;
    float acc = 0.0f;
#pragma unroll
    for (int r = 0; r < NXCC; ++r) acc += yrep[(size_t)r * N_NODES + n];
    y[n] = acc;
}

extern "C" void kernel_launch(void* const* d_in, const int* in_sizes, int n_in,
                              void* d_out, int out_size, void* d_ws, size_t ws_size,
                              hipStream_t stream) {
    const float* X    = (const float*)d_in[0];
    const int*   rows = (const int*)  d_in[1];
    const int*   cols = (const int*)  d_in[2];
    const float* vals = (const float*)d_in[3];
    const float* h    = (const float*)d_in[4];
    float* y = (float*)d_out;

    char* ws = (char*)d_ws;
    float* Zt = (float*)ws;                                    //  2,000,000 B
    size_t counts_off  = 2000000;                              //    200,000 B
    size_t spill_off   = counts_off + 200000;                  //    400,000 B
    size_t binned_off  = spill_off + 400000;
    size_t binned_sz   = (size_t)NCHUNK * NB * WCAP * 4;       // 102,400,000 B
    size_t partial_off = binned_off + binned_sz;
    size_t partial_sz  = (size_t)NB * BPB * ROWS_PB * 4;       //  38,400,000 B
    size_t need = partial_off + partial_sz;                    // ~143.4 MB

    {   // Z = X @ h  (Zt layout [k][n])
        int threads = 256;
        int blocks  = (N_NODES + threads - 1) / threads;
        compute_z_kernel<<<blocks, threads, 0, stream>>>(X, h, Zt);
    }

    if (ws_size >= need) {
        int*          counts   = (int*)(ws + counts_off);
        float*        spill    = (float*)(ws + spill_off);
        unsigned int* binned   = (unsigned int*)(ws + binned_off);
        float*        partials = (float*)(ws + partial_off);
        hipMemsetAsync(spill, 0, 400000, stream);
        scatter_kernel<<<NCHUNK, 256, 0, stream>>>(rows, cols, vals, Zt,
                                                   binned, counts, spill);
        accum_kernel<<<NB * BPB, 256, 0, stream>>>(binned, counts, partials);
        {
            int threads = 256;
            int blocks  = (N_NODES + threads - 1) / threads;
            reduce_kernel<<<blocks, threads, 0, stream>>>(partials, spill, y);
        }
    } else {
        // fallback: R3 far-atomic path
        float* yrep = (float*)(ws + spill_off);
        hipMemsetAsync(yrep, 0, (size_t)NXCC * N_NODES * sizeof(float), stream);
        {
            int threads = 256;
            int blocks = ((KK * EE) / 4 + threads - 1) / threads;
            edge_kernel_atomic<<<blocks, threads, 0, stream>>>(rows, cols, vals, Zt, yrep);
        }
        {
            int threads = 256;
            int blocks  = (N_NODES + threads - 1) / threads;
            reduce8_kernel<<<blocks, threads, 0, stream>>>(yrep, y);
        }
    }
}

// Round 2
// 358.625 us; speedup vs baseline: 1.1103x; 1.0117x over previous
//
#include <hip/hip_runtime.h>
#include <hip/hip_fp16.h>

#define N_NODES 100000
#define KK 5
#define CC 16
#define EE 3200000
#define NXCC 8

#define NB 16                // row buckets
#define ROWS_PB 6250         // N_NODES / NB
#define WCAP 512             // entries per (block,bucket) window: mean 320, +11 sigma
#define WPAD 513             // LDS stride: bucket bases land on distinct banks
#define BPB 96               // accum blocks per bucket (16*96 = 1536 blocks, 6/CU)
#define CHUNK 5120           // edges per scatter block
#define NCHUNK 3125          // 3125 * 5120 = 16,000,000
#define GROUPS 5             // CHUNK / (256*4)
#define BLK_PER_K 625        // EE / CHUNK

__device__ __forceinline__ int xcc_id() {
    int x;
    asm volatile("s_getreg_b32 %0, hwreg(HW_REG_XCC_ID)" : "=s"(x));
    return x & (NXCC - 1);
}

// Kernel 1: Zt[k*N + n] = sum_c X[n,c] * h[c,k]
__global__ void compute_z_kernel(const float* __restrict__ X,
                                 const float* __restrict__ h,
                                 float* __restrict__ Zt) {
    int n = blockIdx.x * blockDim.x + threadIdx.x;
    if (n >= N_NODES) return;
    const float4* Xr = (const float4*)(X + (size_t)n * CC);
    float4 x0 = Xr[0], x1 = Xr[1], x2 = Xr[2], x3 = Xr[3];
    float xv[CC] = {x0.x, x0.y, x0.z, x0.w, x1.x, x1.y, x1.z, x1.w,
                    x2.x, x2.y, x2.z, x2.w, x3.x, x3.y, x3.z, x3.w};
#pragma unroll
    for (int k = 0; k < KK; ++k) {
        float acc = 0.0f;
#pragma unroll
        for (int c = 0; c < CC; ++c) acc += xv[c] * h[c * KK + k];
        Zt[k * N_NODES + n] = acc;
    }
}

// Phase A (R6): R5 showed VGPR=52 (allocator re-serialized the phases) and
// scattered phase-4 stores (~16 transactions per wave store across bucket
// regions 6.4 MB apart). Now: pack into a 32 KB LDS buffer (padded stride 513
// so bucket bases hit distinct banks), then flush each bucket COALESCED.
// Scattered global stores -> ds_write + ~20 coalesced wave stores; z feeds
// the lgkm domain so the 20 gathers can stay batched in the vm queue.
__global__ __launch_bounds__(256, 2)
void scatter_kernel(const int* __restrict__ rows,
                    const int* __restrict__ cols,
                    const float* __restrict__ vals,
                    const float* __restrict__ Zt,
                    unsigned int* __restrict__ binned,
                    int* __restrict__ counts,
                    float* __restrict__ spill) {
    __shared__ int lcnt[NB];
    __shared__ unsigned int buf[NB * WPAD];           // 32.8 KB -> 4 blocks/CU
    int tid = threadIdx.x;
    if (tid < NB) lcnt[tid] = 0;
    __syncthreads();

    int w = blockIdx.x;
    int cbase = w * CHUNK;
    const float* Zk = Zt + (size_t)(w / BLK_PER_K) * N_NODES;   // block shares one k

    // ---- phase 1: all inputs (15 dwordx4 loads in flight) ----
    int4   r4[GROUPS], c4[GROUPS];
    float4 v4[GROUPS];
#pragma unroll
    for (int g = 0; g < GROUPS; ++g) {
        int e = cbase + (g * 256 + tid) * 4;
        r4[g] = *(const int4*)(rows + e);
        c4[g] = *(const int4*)(cols + e);
        v4[g] = *(const float4*)(vals + e);
    }

    // ---- phase 2: all 20 gathers issued before any consumer ----
    float z[GROUPS * 4];
#pragma unroll
    for (int g = 0; g < GROUPS; ++g) {
        z[4 * g + 0] = Zk[c4[g].x];
        z[4 * g + 1] = Zk[c4[g].y];
        z[4 * g + 2] = Zk[c4[g].z];
        z[4 * g + 3] = Zk[c4[g].w];
    }

    // ---- phase 3: LDS position allocation, overlaps in-flight gathers ----
    int pos[GROUPS * 4];
#pragma unroll
    for (int g = 0; g < GROUPS; ++g) {
        int rr[4] = {r4[g].x, r4[g].y, r4[g].z, r4[g].w};
#pragma unroll
        for (int i = 0; i < 4; ++i) {
            int b = rr[i] / ROWS_PB;                  // compiler magic-mul
            pos[4 * g + i] = atomicAdd(&lcnt[b], 1);
        }
    }

    // ---- phase 4: pack + ds_write into staging buffer ----
#pragma unroll
    for (int g = 0; g < GROUPS; ++g) {
        int   rr[4] = {r4[g].x, r4[g].y, r4[g].z, r4[g].w};
        float vv[4] = {v4[g].x, v4[g].y, v4[g].z, v4[g].w};
#pragma unroll
        for (int i = 0; i < 4; ++i) {
            int b = rr[i] / ROWS_PB;
            float cb = vv[i] * z[4 * g + i];
            int p = pos[4 * g + i];
            if (p < WCAP) {
                unsigned int packed =
                    ((unsigned)(rr[i] - b * ROWS_PB) << 16) |
                    (unsigned)__half_as_ushort(__float2half_rn(cb));
                buf[b * WPAD + p] = packed;
            } else {
                unsafeAtomicAdd(&spill[rr[i]], cb);   // exact, ~never taken
            }
        }
    }
    __syncthreads();

    // ---- phase 5: coalesced flush, bucket-major global layout [b][w][WCAP] --
    unsigned int* wbase = binned + (size_t)w * WCAP;
#pragma unroll 1
    for (int b = 0; b < NB; ++b) {
        int cnt = min(lcnt[b], WCAP);                 // wave-uniform (LDS bcast)
        unsigned int* dst = wbase + (size_t)b * ((size_t)NCHUNK * WCAP);
        for (int i = tid; i < cnt; i += 256)
            dst[i] = buf[b * WPAD + i];
    }
    if (tid < NB) counts[w * NB + tid] = min(lcnt[tid], WCAP);
}

// Phase B: counts preloaded to LDS once; 4 windows x 2 position-strips = 8
// UNPREDICATED loads in flight per thread (reads past cnt are within the
// allocated window -> harmless; only the atomic is predicated), then the
// ds_add burst. binned is bucket-major so the read stream is near-contiguous.
__global__ void accum_kernel(const unsigned int* __restrict__ binned,
                             const int* __restrict__ counts,
                             float* __restrict__ partials) {
    __shared__ float acc[ROWS_PB];                    // 25 KB
    __shared__ int cnts[40];                          // whi-wlo <= 33
    int b = blockIdx.x / BPB;
    int s = blockIdx.x % BPB;
    int tid = threadIdx.x;
    int wlo = (NCHUNK * s) / BPB;
    int whi = (NCHUNK * (s + 1)) / BPB;
    for (int i = tid; i < ROWS_PB; i += 256) acc[i] = 0.0f;
    if (tid < whi - wlo) cnts[tid] = counts[(wlo + tid) * NB + b];
    __syncthreads();

    const unsigned int* bbase = binned + (size_t)b * ((size_t)NCHUNK * WCAP);
    for (int w0 = wlo; w0 < whi; w0 += 4) {
        unsigned int e[8];
        int ok[8];
#pragma unroll
        for (int j = 0; j < 4; ++j) {
            int w = w0 + j;
            int in = w < whi;
            int cnt = in ? cnts[w - wlo] : 0;
            const unsigned int* src = bbase + (size_t)(in ? w : wlo) * WCAP;
            ok[2 * j]     = tid < cnt;
            ok[2 * j + 1] = tid + 256 < cnt;
            e[2 * j]      = src[tid];                 // unpredicated: window is
            e[2 * j + 1]  = src[tid + 256];           // allocated, garbage ok
        }
#pragma unroll
        for (int q = 0; q < 8; ++q)
            if (ok[q])
                atomicAdd(&acc[e[q] >> 16],
                          __half2float(__ushort_as_half((unsigned short)(e[q] & 0xFFFFu))));
    }
    __syncthreads();
    float* dst = partials + (size_t)blockIdx.x * ROWS_PB;
    for (int i = tid; i < ROWS_PB; i += 256) dst[i] = acc[i];
}

// y[n] = spill[n] + sum over BPB partial slices of n's bucket
__global__ void reduce_kernel(const float* __restrict__ partials,
                              const float* __restrict__ spill,
                              float* __restrict__ y) {
    int n = blockIdx.x * blockDim.x + threadIdx.x;
    if (n >= N_NODES) return;
    int b = n / ROWS_PB, loc = n - b * ROWS_PB;
    const float* p = partials + (size_t)(b * BPB) * ROWS_PB + loc;
    float acc = spill[n];
#pragma unroll 8
    for (int s = 0; s < BPB; ++s) acc += p[(size_t)s * ROWS_PB];
    y[n] = acc;
}

// ---------- fallback path (R3): far-atomic scatter, used if ws too small ----
__global__ void edge_kernel_atomic(const int* __restrict__ rows,
                                   const int* __restrict__ cols,
                                   const float* __restrict__ vals,
                                   const float* __restrict__ Zt,
                                   float* __restrict__ yrep) {
    int t = blockIdx.x * blockDim.x + threadIdx.x;
    int base = t * 4;
    if (base >= KK * EE) return;
    int k = base / EE;
    const float* Zk = Zt + (size_t)k * N_NODES;
    float* y = yrep + (size_t)xcc_id() * N_NODES;
    int4 r = *(const int4*)(rows + base);
    int4 c = *(const int4*)(cols + base);
    float4 v = *(const float4*)(vals + base);
    unsafeAtomicAdd(&y[r.x], v.x * Zk[c.x]);
    unsafeAtomicAdd(&y[r.y], v.y * Zk[c.y]);
    unsafeAtomicAdd(&y[r.z], v.z * Zk[c.z]);
    unsafeAtomicAdd(&y[r.w], v.w * Zk[c.w]);
}

__global__ void reduce8_kernel(const float* __restrict__ yrep, float* __restrict__ y) {
    int n = blockIdx.x * blockDim.x + threadIdx.x;
    if (n >= N_NODES) return;
    float acc = 0.0f;
#pragma unroll
    for (int r = 0; r < NXCC; ++r) acc += yrep[(size_t)r * N_NODES + n];
    y[n] = acc;
}

extern "C" void kernel_launch(void* const* d_in, const int* in_sizes, int n_in,
                              void* d_out, int out_size, void* d_ws, size_t ws_size,
                              hipStream_t stream) {
    const float* X    = (const float*)d_in[0];
    const int*   rows = (const int*)  d_in[1];
    const int*   cols = (const int*)  d_in[2];
    const float* vals = (const float*)d_in[3];
    const float* h    = (const float*)d_in[4];
    float* y = (float*)d_out;

    char* ws = (char*)d_ws;
    float* Zt = (float*)ws;                                    //  2,000,000 B
    size_t counts_off  = 2000000;                              //    200,000 B
    size_t spill_off   = counts_off + 200000;                  //    400,000 B
    size_t binned_off  = spill_off + 400000;
    size_t binned_sz   = (size_t)NCHUNK * NB * WCAP * 4;       // 102,400,000 B
    size_t partial_off = binned_off + binned_sz;
    size_t partial_sz  = (size_t)NB * BPB * ROWS_PB * 4;       //  38,400,000 B
    size_t need = partial_off + partial_sz;                    // ~143.4 MB

    {   // Z = X @ h  (Zt layout [k][n])
        int threads = 256;
        int blocks  = (N_NODES + threads - 1) / threads;
        compute_z_kernel<<<blocks, threads, 0, stream>>>(X, h, Zt);
    }

    if (ws_size >= need) {
        int*          counts   = (int*)(ws + counts_off);
        float*        spill    = (float*)(ws + spill_off);
        unsigned int* binned   = (unsigned int*)(ws + binned_off);
        float*        partials = (float*)(ws + partial_off);
        hipMemsetAsync(spill, 0, 400000, stream);
        scatter_kernel<<<NCHUNK, 256, 0, stream>>>(rows, cols, vals, Zt,
                                                   binned, counts, spill);
        accum_kernel<<<NB * BPB, 256, 0, stream>>>(binned, counts, partials);
        {
            int threads = 256;
            int blocks  = (N_NODES + threads - 1) / threads;
            reduce_kernel<<<blocks, threads, 0, stream>>>(partials, spill, y);
        }
    } else {
        // fallback: R3 far-atomic path
        float* yrep = (float*)(ws + spill_off);
        hipMemsetAsync(yrep, 0, (size_t)NXCC * N_NODES * sizeof(float), stream);
        {
            int threads = 256;
            int blocks = ((KK * EE) / 4 + threads - 1) / threads;
            edge_kernel_atomic<<<blocks, threads, 0, stream>>>(rows, cols, vals, Zt, yrep);
        }
        {
            int threads = 256;
            int blocks  = (N_NODES + threads - 1) / threads;
            reduce8_kernel<<<blocks, threads, 0, stream>>>(yrep, y);
        }
    }
}